// Round 4
// baseline (295.212 us; speedup 1.0000x reference)
//
#include <hip/hip_runtime.h>
#include <hip/hip_bf16.h>

#define NEG_INF -1e20f

typedef __bf16 bf16x8 __attribute__((ext_vector_type(8)));
typedef float  f32x4  __attribute__((ext_vector_type(4)));

__device__ inline unsigned short f2bf(float x) {            // RNE, no NaN inputs
    unsigned u = __float_as_uint(x);
    unsigned r = u + 0x7fffu + ((u >> 16) & 1u);
    return (unsigned short)(r >> 16);
}
__device__ inline float bf2f(unsigned short h) {
    return __uint_as_float((unsigned)h << 16);
}
__device__ inline unsigned fkey(float f) {
    unsigned u = __float_as_uint(f);
    return (u & 0x80000000u) ? ~u : (u | 0x80000000u);
}
__device__ inline float unfkey(unsigned k) {
    unsigned fu = (k & 0x80000000u) ? (k ^ 0x80000000u) : ~k;
    return __uint_as_float(fu);
}

// ---------------------------------------------------------------------------
// K0: split ctx AND W into 3 bf16 planes each, one launch. VERBATIM R0.
// ---------------------------------------------------------------------------
__global__ __launch_bounds__(256) void split3_all(
        const float* __restrict__ ctx, const float* __restrict__ W,
        unsigned short* __restrict__ C1, unsigned short* __restrict__ C2,
        unsigned short* __restrict__ C3, unsigned short* __restrict__ W1,
        unsigned short* __restrict__ W2, unsigned short* __restrict__ W3) {
    const int b = blockIdx.x;
    const int t = threadIdx.x;
    const float* src;
    unsigned short *p1, *p2, *p3;
    int base;
    if (b < 2048) { src = ctx; p1 = C1; p2 = C2; p3 = C3; base = b * 1024; }
    else          { src = W;   p1 = W1; p2 = W2; p3 = W3; base = (b - 2048) * 1024; }
#pragma unroll
    for (int it = 0; it < 4; ++it) {
        int i = base + it * 256 + t;
        float4 v = ((const float4*)src)[i];
        ushort4 a, bb, c;
        float r;
        a.x = f2bf(v.x); r = v.x - bf2f(a.x); bb.x = f2bf(r); c.x = f2bf(r - bf2f(bb.x));
        a.y = f2bf(v.y); r = v.y - bf2f(a.y); bb.y = f2bf(r); c.y = f2bf(r - bf2f(bb.y));
        a.z = f2bf(v.z); r = v.z - bf2f(a.z); bb.z = f2bf(r); c.z = f2bf(r - bf2f(bb.z));
        a.w = f2bf(v.w); r = v.w - bf2f(a.w); bb.w = f2bf(r); c.w = f2bf(r - bf2f(bb.w));
        ((ushort4*)p1)[i] = a;
        ((ushort4*)p2)[i] = bb;
        ((ushort4*)p3)[i] = c;
    }
}

// ---------------------------------------------------------------------------
// K1: ctx_fc = relu(context @ W^T) via 6-term bf16 MFMA, 128x128 tile. VERBATIM R0.
// ---------------------------------------------------------------------------
__global__ __launch_bounds__(256, 2) void fc_mfma6(
        const unsigned short* __restrict__ A1, const unsigned short* __restrict__ A2,
        const unsigned short* __restrict__ A3, const unsigned short* __restrict__ B1,
        const unsigned short* __restrict__ B2, const unsigned short* __restrict__ B3,
        unsigned short* __restrict__ Fhi, unsigned short* __restrict__ Flo) {
    __shared__ char lds[49152];

    const int t     = threadIdx.x;
    const int mBase = blockIdx.x * 128;
    const int hBase = blockIdx.y * 128;
    const int w = t >> 6, lane = t & 63;
    const int q = lane >> 4, ln = lane & 15;
    const int wn = (w >> 1) * 64;
    const int wm = (w & 1) * 64;

    f32x4 acc[4][4] = {};

    for (int kt = 0; kt < 512; kt += 32) {
#pragma unroll
        for (int p = 0; p < 3; ++p) {
            const unsigned short* pl = (p == 0) ? A1 : (p == 1) ? A2 : A3;
#pragma unroll
            for (int rr = 0; rr < 2; ++rr) {
                int chunk = rr * 256 + t;
                int row   = chunk >> 2;
                int c     = (chunk & 3) ^ ((row >> 1) & 3);
                const unsigned short* g = pl + ((size_t)(mBase + row) * 512 + kt + c * 8);
                char* l = lds + p * 8192 + chunk * 16;
                __builtin_amdgcn_global_load_lds(
                    (const __attribute__((address_space(1))) void*)g,
                    (__attribute__((address_space(3))) void*)l, 16, 0, 0);
            }
        }
#pragma unroll
        for (int p = 0; p < 3; ++p) {
            const unsigned short* pl = (p == 0) ? B1 : (p == 1) ? B2 : B3;
#pragma unroll
            for (int rr = 0; rr < 2; ++rr) {
                int chunk = rr * 256 + t;
                int row   = chunk >> 2;
                int c     = (chunk & 3) ^ ((row >> 1) & 3);
                const unsigned short* g = pl + ((size_t)(hBase + row) * 512 + kt + c * 8);
                char* l = lds + 24576 + p * 8192 + chunk * 16;
                __builtin_amdgcn_global_load_lds(
                    (const __attribute__((address_space(1))) void*)g,
                    (__attribute__((address_space(3))) void*)l, 16, 0, 0);
            }
        }
        __syncthreads();

        bf16x8 a1[4], a2[4], a3[4], b1[4], b2[4], b3[4];
#pragma unroll
        for (int i = 0; i < 4; ++i) {
            int mA = wn + i * 16 + ln;
            int oA = (mA * 4 + (q ^ ((mA >> 1) & 3))) * 16;
            a1[i] = *(const bf16x8*)(lds +     0 + oA);
            a2[i] = *(const bf16x8*)(lds +  8192 + oA);
            a3[i] = *(const bf16x8*)(lds + 16384 + oA);
            int mB = wm + i * 16 + ln;
            int oB = (mB * 4 + (q ^ ((mB >> 1) & 3))) * 16;
            b1[i] = *(const bf16x8*)(lds + 24576 + oB);
            b2[i] = *(const bf16x8*)(lds + 32768 + oB);
            b3[i] = *(const bf16x8*)(lds + 40960 + oB);
        }
#pragma unroll
        for (int i = 0; i < 4; ++i)
#pragma unroll
            for (int j = 0; j < 4; ++j) {
                acc[i][j] = __builtin_amdgcn_mfma_f32_16x16x32_bf16(a1[i], b1[j], acc[i][j], 0, 0, 0);
                acc[i][j] = __builtin_amdgcn_mfma_f32_16x16x32_bf16(a1[i], b2[j], acc[i][j], 0, 0, 0);
                acc[i][j] = __builtin_amdgcn_mfma_f32_16x16x32_bf16(a2[i], b1[j], acc[i][j], 0, 0, 0);
                acc[i][j] = __builtin_amdgcn_mfma_f32_16x16x32_bf16(a2[i], b2[j], acc[i][j], 0, 0, 0);
                acc[i][j] = __builtin_amdgcn_mfma_f32_16x16x32_bf16(a1[i], b3[j], acc[i][j], 0, 0, 0);
                acc[i][j] = __builtin_amdgcn_mfma_f32_16x16x32_bf16(a3[i], b1[j], acc[i][j], 0, 0, 0);
            }
        __syncthreads();
    }

    unsigned* tb = (unsigned*)(lds + w * 4352);
    const int rg = lane >> 4;
    const int c4 = lane & 15;
#pragma unroll
    for (int i = 0; i < 4; ++i) {
#pragma unroll
        for (int j = 0; j < 4; ++j)
#pragma unroll
            for (int r = 0; r < 4; ++r) {
                float v = fmaxf(acc[i][j][r], 0.f);
                unsigned short hi = f2bf(v);
                unsigned short lo = f2bf(v - bf2f(hi));
                tb[(q * 4 + r) * 68 + j * 16 + ln] =
                    (unsigned)hi | ((unsigned)lo << 16);
            }
#pragma unroll
        for (int it = 0; it < 4; ++it) {
            int row = it * 4 + rg;
            uint4 pk = *(const uint4*)&tb[row * 68 + c4 * 4];
            ushort4 h, l;
            h.x = (unsigned short)pk.x; l.x = (unsigned short)(pk.x >> 16);
            h.y = (unsigned short)pk.y; l.y = (unsigned short)(pk.y >> 16);
            h.z = (unsigned short)pk.z; l.z = (unsigned short)(pk.z >> 16);
            h.w = (unsigned short)pk.w; l.w = (unsigned short)(pk.w >> 16);
            size_t off = (size_t)(mBase + wn + i * 16 + row) * 512 + hBase + wm + c4 * 4;
            *(ushort4*)(Fhi + off) = h;
            *(ushort4*)(Flo + off) = l;
        }
    }
}

// ---------------------------------------------------------------------------
// K2: att = F F^T via bf16x3 MFMA — symmetric pairs + per-64-col-half maxima
// to cv2. VERBATIM R3.
// ---------------------------------------------------------------------------
__global__ __launch_bounds__(256, 3) void att_sym_cand(
        const unsigned short* __restrict__ Fhi, const unsigned short* __restrict__ Flo,
        const int* __restrict__ mask, float* __restrict__ out,
        float* __restrict__ cv2) {
    __shared__ char lds[32768];

    const int t = threadIdx.x;
    const int b = blockIdx.x & 7;        // XCD-pinned batch
    int p = blockIdx.x >> 3, ti = 0;     // pair 0..135
    while (p >= 16 - ti) { p -= 16 - ti; ++ti; }
    const int tj = ti + p;
    const int nBase = ti * 128;
    const int mBase = tj * 128;
    const int w    = t >> 6, lane = t & 63;
    const int q    = lane >> 4, ln = lane & 15;
    const int wn   = (w >> 1) * 64;
    const int wm   = (w & 1) * 64;
    const size_t rowB = (size_t)b * 2048;

    f32x4 acc[4][4] = {};

    for (int kt = 0; kt < 512; kt += 32) {
#pragma unroll
        for (int pp = 0; pp < 4; ++pp) {
            const unsigned short* plane = (pp & 1) ? Flo : Fhi;
            int rbase = (pp < 2) ? nBase : mBase;
#pragma unroll
            for (int r = 0; r < 2; ++r) {
                int chunk = r * 256 + t;
                int row   = chunk >> 2;
                int c     = (chunk & 3) ^ ((row >> 1) & 3);
                const unsigned short* g =
                    plane + ((rowB + rbase + row) * 512 + kt + c * 8);
                char* l = lds + pp * 8192 + chunk * 16;
                __builtin_amdgcn_global_load_lds(
                    (const __attribute__((address_space(1))) void*)g,
                    (__attribute__((address_space(3))) void*)l, 16, 0, 0);
            }
        }
        __syncthreads();

        bf16x8 ah[4], al[4], bh[4], bl[4];
#pragma unroll
        for (int i = 0; i < 4; ++i) {
            int mA = wn + i * 16 + ln;
            int oA = (mA * 4 + (q ^ ((mA >> 1) & 3))) * 16;
            ah[i] = *(const bf16x8*)(lds +     0 + oA);
            al[i] = *(const bf16x8*)(lds +  8192 + oA);
            int mB = wm + i * 16 + ln;
            int oB = (mB * 4 + (q ^ ((mB >> 1) & 3))) * 16;
            bh[i] = *(const bf16x8*)(lds + 16384 + oB);
            bl[i] = *(const bf16x8*)(lds + 24576 + oB);
        }
#pragma unroll
        for (int i = 0; i < 4; ++i)
#pragma unroll
            for (int j = 0; j < 4; ++j) {
                acc[i][j] = __builtin_amdgcn_mfma_f32_16x16x32_bf16(ah[i], bh[j], acc[i][j], 0, 0, 0);
                acc[i][j] = __builtin_amdgcn_mfma_f32_16x16x32_bf16(ah[i], bl[j], acc[i][j], 0, 0, 0);
                acc[i][j] = __builtin_amdgcn_mfma_f32_16x16x32_bf16(al[i], bh[j], acc[i][j], 0, 0, 0);
            }
        __syncthreads();
    }

    const int* mb = mask + b * 2048;
    float* outB = out + (size_t)b * 2048 * 2048;
    int cmj[4];
#pragma unroll
    for (int j = 0; j < 4; ++j) cmj[j] = mb[mBase + wm + j * 16 + ln];
    int rmAll[4][4];
#pragma unroll
    for (int i = 0; i < 4; ++i)
#pragma unroll
        for (int r = 0; r < 4; ++r) rmAll[i][r] = mb[nBase + wn + i * 16 + q * 4 + r];

    float* tb = (float*)(lds + w * 4352);
    const int rg = lane >> 4;
    const int c4 = lane & 15;
    const bool mirror = (ti != tj);
#pragma unroll
    for (int i = 0; i < 4; ++i) {
        int n0 = nBase + wn + i * 16;
        // --- candidate: per-row max over this wave's 64-col half ---
#pragma unroll
        for (int r = 0; r < 4; ++r) {
            float m4 = NEG_INF;
#pragma unroll
            for (int j = 0; j < 4; ++j) {
                float v = ((rmAll[i][r] != 0) & (cmj[j] != 0)) ? acc[i][j][r] : NEG_INF;
                m4 = fmaxf(m4, v);
            }
            m4 = fmaxf(m4, __shfl_xor(m4, 1, 64));
            m4 = fmaxf(m4, __shfl_xor(m4, 2, 64));
            m4 = fmaxf(m4, __shfl_xor(m4, 4, 64));
            m4 = fmaxf(m4, __shfl_xor(m4, 8, 64));
            if (ln == 0)
                cv2[(rowB + n0 + q * 4 + r) * 32 + tj * 2 + (w & 1)] = m4;
        }
        // --- matrix write ---
#pragma unroll
        for (int j = 0; j < 4; ++j)
#pragma unroll
            for (int r = 0; r < 4; ++r) {
                float v = ((rmAll[i][r] != 0) & (cmj[j] != 0)) ? acc[i][j][r] : NEG_INF;
                tb[(q * 4 + r) * 68 + j * 16 + ln] = v;
            }
#pragma unroll
        for (int it = 0; it < 4; ++it) {
            int row = it * 4 + rg;
            float4 vv = *(const float4*)&tb[row * 68 + c4 * 4];
            *(float4*)(outB + (size_t)(n0 + row) * 2048 + mBase + wm + c4 * 4) = vv;
        }
        if (mirror) {
#pragma unroll
            for (int ps = 0; ps < 4; ++ps) {
                float4 mv;
                mv.x = tb[(ps * 4 + 0) * 68 + lane];
                mv.y = tb[(ps * 4 + 1) * 68 + lane];
                mv.z = tb[(ps * 4 + 2) * 68 + lane];
                mv.w = tb[(ps * 4 + 3) * 68 + lane];
                *(float4*)(outB + (size_t)(mBase + wm + lane) * 2048 + n0 + ps * 4) = mv;
            }
        }
    }
    // --- mirror candidates ---
    if (mirror) {
#pragma unroll
        for (int j = 0; j < 4; ++j) {
            float m16 = NEG_INF;
#pragma unroll
            for (int i2 = 0; i2 < 4; ++i2)
#pragma unroll
                for (int r = 0; r < 4; ++r) {
                    float v = ((rmAll[i2][r] != 0) & (cmj[j] != 0)) ? acc[i2][j][r] : NEG_INF;
                    m16 = fmaxf(m16, v);
                }
            m16 = fmaxf(m16, __shfl_xor(m16, 16, 64));
            m16 = fmaxf(m16, __shfl_xor(m16, 32, 64));
            if (q == 0)
                cv2[(rowB + mBase + wm + j * 16 + ln) * 32 + ti * 2 + (w >> 1)] = m16;
        }
    }
}

// ---------------------------------------------------------------------------
// K3 v2: threshold-filtered per-row top-10, register-direct output.
//  - L = 10th-largest of 32 half-maxima (exact lower bound on true 10th).
//  - Load ONLY selected halves (<=16; one coalesced 256 B load each, all
//    issued up-front -> no serial load->ballot chains).
//  - <=16 ballot-compact rounds into a 512 B/wave LDS table; rank-select;
//    winners broadcast via an 80 B LDS array (wave-local, no barriers).
//  - Output written directly from registers (no 2 KB LDS patch round-trip).
//  LDS ~2.4 KB/block -> 8 blocks/CU for latency hiding.
//  Fallback (nsel>16 or nsurv>64): verbatim R13 full extraction.
// ---------------------------------------------------------------------------
__global__ __launch_bounds__(256) void topk_filter(
        const float* __restrict__ cv2, float* __restrict__ att) {
    __shared__ float2 surv[4][64];
    __shared__ float2 win[4][10];

    const int t = threadIdx.x, w = t >> 6, lane = t & 63;
    const size_t R = (size_t)blockIdx.x * 4 + w;      // global row 0..16383
    float* row = att + R * 2048;

    // ---- L = 10th-largest of 32 half-maxima (rank via shuffle broadcast) ----
    float cnd = (lane < 32) ? cv2[R * 32 + lane] : NEG_INF;
    int rk = 0;
#pragma unroll
    for (int j = 0; j < 32; ++j) {
        float vj = __shfl(cnd, j, 64);
        rk += ((vj > cnd) || (vj == cnd && j < lane)) ? 1 : 0;
    }
    unsigned long long bl = __ballot((lane < 32) && (rk == 9));
    float L = __shfl(cnd, __ffsll(bl) - 1, 64);
    unsigned long long hsel = __ballot((lane < 32) && (cnd >= L));
    const int nsel = (int)__popcll(hsel);          // >= 10 always

    const bool ok = (nsel <= 16);
    float v[16]; int hcol[16]; bool hv[16];
    if (ok) {
        unsigned long long m = hsel;
#pragma unroll
        for (int k = 0; k < 16; ++k) {
            hv[k] = (m != 0);
            int h = hv[k] ? (__ffsll(m) - 1) : 0;   // invalid -> dup half 0 (L1 hit)
            m &= (m - 1);
            hcol[k] = h * 64 + lane;
            v[k] = row[h * 64 + lane];              // 256 B coalesced per k
        }
    }

    // ---- ballot-compact survivors (v >= L) into LDS ----
    int nsurv = 0;
    if (ok) {
        const unsigned long long lmask = (1ull << lane) - 1;
#pragma unroll
        for (int k = 0; k < 16; ++k) {
            bool pr = hv[k] && (v[k] >= L);
            unsigned long long pb = __ballot(pr);
            if (pr) {
                int idx = nsurv + (int)__popcll(pb & lmask);
                if (idx < 64) surv[w][idx] = make_float2(v[k], __int_as_float(hcol[k]));
            }
            nsurv += (int)__popcll(pb);
        }
    }

    if (ok && nsurv <= 64) {
        // ---- rank-select top-10 among survivors (value desc, col asc) ----
        float sv = NEG_INF; int sc = 0x7fffffff;
        if (lane < nsurv) {
            float2 s2 = surv[w][lane];
            sv = s2.x; sc = __float_as_int(s2.y);
        }
        int r2 = 0;
        for (int j = 0; j < nsurv; ++j) {
            float2 sj = surv[w][j];               // LDS broadcast read
            int cj = __float_as_int(sj.y);
            r2 += ((sj.x > sv) || (sj.x == sv && cj < sc)) ? 1 : 0;
        }
        if ((lane < nsurv) && (r2 < 10))          // nsurv >= nsel >= 10 always
            win[w][r2] = make_float2(sv, __int_as_float(sc));
    } else {
        // ---- fallback: verbatim R13 full extraction (reload full row) ----
        unsigned key[32];
#pragma unroll
        for (int s = 0; s < 8; ++s) {
            float4 vv = *(const float4*)(row + lane * 32 + s * 4);
            key[s * 4 + 0] = fkey(vv.x);
            key[s * 4 + 1] = fkey(vv.y);
            key[s * 4 + 2] = fkey(vv.z);
            key[s * 4 + 3] = fkey(vv.w);
        }
        unsigned h1 = key[0]; int i1 = 0;
#pragma unroll
        for (int j = 1; j < 32; ++j)
            if (key[j] > h1) { h1 = key[j]; i1 = j; }
        unsigned h2 = 0; int i2 = 0;
#pragma unroll
        for (int j = 0; j < 32; ++j) {
            bool okb = (j != i1) && (key[j] > h2);
            h2 = okb ? key[j] : h2;
            i2 = okb ? j : i2;
        }
        bool h2valid = true;
        unsigned taken = 0;
        for (int r = 0; r < 10; ++r) {
            unsigned M = h1;
#pragma unroll
            for (int off = 1; off < 64; off <<= 1) {
                unsigned o = __shfl_xor(M, off, 64);
                M = (o > M) ? o : M;
            }
            unsigned long long ball = __ballot(h1 == M);
            int srcb = __ffsll(ball) - 1;
            int wloc = __shfl(i1, srcb, 64);
            if (lane == r) win[w][r] = make_float2(unfkey(M), __int_as_float(srcb * 32 + wloc));
            if (lane == srcb) {
                taken |= 1u << i1;
                if (h2valid) { h1 = h2; i1 = i2; h2valid = false; }
                else {
                    unsigned bh = 0; int bi = 0;
#pragma unroll
                    for (int j = 0; j < 32; ++j) {
                        bool okb = (((taken >> j) & 1u) == 0u) && (key[j] > bh);
                        bh = okb ? key[j] : bh;
                        bi = okb ? j : bi;
                    }
                    h1 = bh; i1 = bi;
                }
            }
        }
    }

    // ---- broadcast winners (wave-local LDS, no barrier) ----
    float wv[10]; int wc[10];
#pragma unroll
    for (int k = 0; k < 10; ++k) {
        float2 wk = win[w][k];
        wv[k] = wk.x; wc[k] = __float_as_int(wk.y);
    }

    // ---- register-direct write: NEG_INF + winner patch ----
#pragma unroll
    for (int s = 0; s < 8; ++s) {
        float4 f4 = make_float4(NEG_INF, NEG_INF, NEG_INF, NEG_INF);
        int cb = s * 256 + lane * 4;              // this lane's 4 global cols
#pragma unroll
        for (int k = 0; k < 10; ++k) {
            if ((wc[k] >> 8) == s) {              // wave-uniform prefilter
                f4.x = (wc[k] == cb + 0) ? wv[k] : f4.x;
                f4.y = (wc[k] == cb + 1) ? wv[k] : f4.y;
                f4.z = (wc[k] == cb + 2) ? wv[k] : f4.z;
                f4.w = (wc[k] == cb + 3) ? wv[k] : f4.w;
            }
        }
        ((float4*)row)[s * 64 + lane] = f4;
    }
}

// ---------------------------------------------------------------------------
extern "C" void kernel_launch(void* const* d_in, const int* in_sizes, int n_in,
                              void* d_out, int out_size, void* d_ws, size_t ws_size,
                              hipStream_t stream) {
    const float* ctx  = (const float*)d_in[0];   // [8, 2048, 512]
    const float* W    = (const float*)d_in[1];   // [512, 512]
    const int*   mask = (const int*)d_in[2];     // [8, 2048]
    float* out = (float*)d_out;                  // [8, 2048, 2048]

    const size_t CN = (size_t)16384 * 512;
    const size_t WN = (size_t)512 * 512;
    // split planes live in the (still-unwritten) 134 MB output buffer;
    // att overwrites them with the matrix AFTER fc has consumed them.
    unsigned short* C1 = (unsigned short*)d_out;
    unsigned short* C2 = C1 + CN;
    unsigned short* C3 = C2 + CN;
    unsigned short* W1 = C3 + CN;
    unsigned short* W2 = W1 + WN;
    unsigned short* W3 = W2 + WN;                // ends at 51.9 MB < 134 MB

    // workspace: cv2 (2 MB) + Fhi/Flo (33.5 MB)
    float* cv2 = (float*)d_ws;                              // [16384][32] f32
    unsigned short* Fhi = (unsigned short*)(cv2 + (size_t)16384 * 32);
    unsigned short* Flo = Fhi + CN;

    dim3 blk(256);
    split3_all<<<dim3(2112), blk, 0, stream>>>(ctx, W, C1, C2, C3, W1, W2, W3);
    fc_mfma6<<<dim3(128, 4), blk, 0, stream>>>(C1, C2, C3, W1, W2, W3, Fhi, Flo);
    att_sym_cand<<<dim3(1088), blk, 0, stream>>>(Fhi, Flo, mask, out, cv2);
    topk_filter<<<dim3(4096), blk, 0, stream>>>(cv2, out);
}